// Round 1
// baseline (784.212 us; speedup 1.0000x reference)
//
#include <hip/hip_runtime.h>

// GlobalFusion R5: k_merge1 staging rework (conflict-free b128 LDS writes +
// T14 register-prefetch pipeline) + k_alpha/k_pool fusion (k_apool).
// Everything else identical to R4 (702 us baseline).

#define DEV static __device__ __forceinline__

typedef __attribute__((ext_vector_type(8))) short short8x;
typedef __attribute__((ext_vector_type(4))) float f32x4;

constexpr int Bc = 2, Vc = 6, Cc = 128, Hc = 128, Wc = 128;
constexpr int Nc = Bc * Vc;      // 12
constexpr int Pc = Hc * Wc;      // 16384
constexpr int NPX = Nc * Pc;     // 196608

DEV float us2f(unsigned short u) {
  return __builtin_bit_cast(float, (unsigned int)u << 16);
}
DEV unsigned short f2us(float f) {
  unsigned int i = __builtin_bit_cast(unsigned int, f);
  unsigned int r = i + 0x7FFFu + ((i >> 16) & 1u);   // RNE
  return (unsigned short)(r >> 16);
}
DEV float geluf(float x) { return x * 0.5f * (1.f + erff(x * 0.70710678118654752f)); }
DEV float sigm(float x) { return 1.f / (1.f + __expf(-x)); }

// ---------------- weight prep: fp32 -> bf16 (+ GRU row interleave) ----------------
__global__ __launch_bounds__(256) void k_prepw(
    const float* __restrict__ w1, const float* __restrict__ w2,
    const float* __restrict__ wu, const float* __restrict__ gw,
    const float* __restrict__ gbw, unsigned short* __restrict__ wbf) {
  int idx = blockIdx.x * 256 + threadIdx.x;
  float v;
  if (idx < 32768) {
    v = w1[idx];
  } else if (idx < 49152) {
    v = w2[idx - 32768];
  } else if (idx < 65536) {
    v = wu[idx - 49152];
  } else {
    int i = (idx < 98304) ? (idx - 65536) : (idx - 98304);
    int np = i >> 7, k = i & 127;
    int j = np >> 5, s = np & 31;
    int src = (s < 16) ? (16 * j + s) : (128 + 16 * j + (s - 16));
    const float* w = (idx < 98304) ? gw : gbw;
    v = w[src * 128 + k];
  }
  wbf[idx] = f2us(v);
}

// ---------------- K1: merge 1x1 conv 256->128 + GELU (MFMA) ----------------
// R5 staging: one px-row per thread, 8-ch octets -> packed b128 LDS writes
// (bank-even, zero excess conflicts), register prefetch of next k-step (T14).
__global__ __launch_bounds__(256) void k_merge1(
    const float* __restrict__ feats, const float* __restrict__ prj,
    const unsigned short* __restrict__ w1b, const float* __restrict__ b1,
    unsigned short* __restrict__ m1, unsigned short* __restrict__ fres) {
  __shared__ unsigned short sA[128][72];
  __shared__ unsigned short sB[128][72];
  const int t = threadIdx.x;
  const int wave = t >> 6, lane = t & 63, quad = lane >> 4, lr = lane & 15;
  const int wm = (wave >> 1) * 64, wn = (wave & 1) * 64;
  const int mb = blockIdx.x;
  const size_t m0 = (size_t)mb * 128;
  const int n = mb >> 7;
  const int p0 = (mb & 127) << 7;

  const int px = t & 127;     // this thread's A-row (wave-contiguous: 64w+lane)
  const int ho = t >> 7;      // 0/1: which half of the 8 channel-octets

  float ra[4][8];             // A prefetch: 4 octets x 8 channels (fp32)
  uint4 rb[4];                // B prefetch: 4 x 16B of w1b

  auto issueA = [&](int k0) {
#pragma unroll
    for (int g = 0; g < 4; ++g) {
      const int ch = k0 + 8 * ho + 16 * g;                 // octet base channel
      const float* src = (ch < 128)
          ? (feats + (size_t)(n * 128 + ch) * Pc)
          : (prj + (size_t)(n * 128 + (ch - 128)) * Pc);
      src += p0 + px;
#pragma unroll
      for (int j = 0; j < 8; ++j) ra[g][j] = src[(size_t)j * Pc];
    }
  };
  auto issueB = [&](int k0) {
#pragma unroll
    for (int u = 0; u < 4; ++u) {
      const int id = u * 256 + t;
      const int row = id >> 3, seg = id & 7;
      rb[u] = *(const uint4*)(w1b + (size_t)row * 256 + k0 + seg * 8);
    }
  };
  auto writeAB = [&]() {
#pragma unroll
    for (int g = 0; g < 4; ++g) {
      unsigned int pk[4];
#pragma unroll
      for (int q2 = 0; q2 < 4; ++q2)
        pk[q2] = (unsigned int)f2us(ra[g][2 * q2]) |
                 ((unsigned int)f2us(ra[g][2 * q2 + 1]) << 16);
      uint4 w4;
      w4.x = pk[0]; w4.y = pk[1]; w4.z = pk[2]; w4.w = pk[3];
      *(uint4*)&sA[px][8 * ho + 16 * g] = w4;   // b128, bank-even across wave
    }
#pragma unroll
    for (int u = 0; u < 4; ++u) {
      const int id = u * 256 + t;
      const int row = id >> 3, seg = id & 7;
      *(uint4*)&sB[row][seg * 8] = rb[u];
    }
  };

  f32x4 acc[4][4];
#pragma unroll
  for (int i = 0; i < 4; i++)
#pragma unroll
    for (int j = 0; j < 4; j++) acc[i][j] = (f32x4){0.f, 0.f, 0.f, 0.f};

  issueA(0);
  issueB(0);
#pragma unroll
  for (int s = 0; s < 4; ++s) {
    const int k0 = s * 64;
    __syncthreads();          // previous MFMA/fres reads of sA/sB done
    writeAB();                // waits vmcnt on prefetched regs (compiler)
    if (s < 3) {              // T14: next step's loads fly over MFMA phase
      issueA(k0 + 64);
      issueB(k0 + 64);
    }
    __syncthreads();
#pragma unroll
    for (int ks = 0; ks < 2; ++ks) {
      const int kk = ks * 32 + quad * 8;
      short8x a[4], bf[4];
#pragma unroll
      for (int i = 0; i < 4; i++)
        a[i] = *reinterpret_cast<const short8x*>(&sA[wm + i * 16 + lr][kk]);
#pragma unroll
      for (int j = 0; j < 4; j++)
        bf[j] = *reinterpret_cast<const short8x*>(&sB[wn + j * 16 + lr][kk]);
#pragma unroll
      for (int i = 0; i < 4; i++)
#pragma unroll
        for (int j = 0; j < 4; j++)
          acc[i][j] = __builtin_amdgcn_mfma_f32_16x16x32_bf16(a[i], bf[j], acc[i][j], 0, 0, 0);
    }
    if (k0 < 128) {   // feats slice passthrough -> fres (reads sA)
      for (int u = t; u < 1024; u += 256) {
        int row = u >> 3, seg = u & 7;
        *(uint4*)(fres + (m0 + row) * 128 + k0 + seg * 8) =
            *(const uint4*)&sA[row][seg * 8];
      }
    }
  }
#pragma unroll
  for (int i = 0; i < 4; i++)
#pragma unroll
    for (int r = 0; r < 4; r++) {
      size_t row = m0 + wm + i * 16 + quad * 4 + r;
#pragma unroll
      for (int j = 0; j < 4; j++) {
        int c = wn + j * 16 + lr;
        m1[row * 128 + c] = f2us(geluf(acc[i][j][r] + b1[c]));
      }
    }
}

// ---------------- K2: depthwise 3x3 + GELU ([px][c] layout) ----------------
__global__ __launch_bounds__(256) void k_dw(
    const unsigned short* __restrict__ in, const float* __restrict__ wd,
    const float* __restrict__ bd, unsigned short* __restrict__ out) {
  __shared__ float w[Cc * 9];
  for (int i = threadIdx.x; i < Cc * 9; i += 256) w[i] = wd[i];
  __syncthreads();
  const int wave = threadIdx.x >> 6, lane = threadIdx.x & 63;
  const int pxg = blockIdx.x * 4 + wave;
  const int n = pxg >> 14, p = pxg & (Pc - 1);
  const int y = p >> 7, x = p & 127;
  const int c0 = 2 * lane;
  float a0 = bd[c0], a1 = bd[c0 + 1];
  const float* w0 = w + c0 * 9;
  const float* w1 = w + (c0 + 1) * 9;
#pragma unroll
  for (int dy = 0; dy < 3; ++dy) {
    int yy = y + dy - 1;
    if (yy < 0 || yy >= Hc) continue;
#pragma unroll
    for (int dx = 0; dx < 3; ++dx) {
      int xx = x + dx - 1;
      if (xx < 0 || xx >= Wc) continue;
      const unsigned short* row = in + ((size_t)(n * Pc + yy * Wc + xx)) * 128;
      ushort2 v = *(const ushort2*)(row + c0);
      a0 += w0[dy * 3 + dx] * us2f(v.x);
      a1 += w1[dy * 3 + dx] * us2f(v.y);
    }
  }
  ushort2 pk;
  pk.x = f2us(geluf(a0));
  pk.y = f2us(geluf(a1));
  *(ushort2*)(out + (size_t)pxg * 128 + c0) = pk;
}

// ---------------- K3: merge 1x1 conv 128->128 + bias + residual (MFMA) ----------------
__global__ __launch_bounds__(256) void k_merge2(
    const unsigned short* __restrict__ A, const unsigned short* __restrict__ w2b,
    const float* __restrict__ b2, const unsigned short* __restrict__ fres,
    unsigned short* __restrict__ X1) {
  __shared__ unsigned short sA[128][72];
  __shared__ unsigned short sB[128][72];
  const int t = threadIdx.x;
  const int wave = t >> 6, lane = t & 63, quad = lane >> 4, lr = lane & 15;
  const int wm = (wave >> 1) * 64, wn = (wave & 1) * 64;
  const size_t m0 = (size_t)blockIdx.x * 128;
  f32x4 acc[4][4];
#pragma unroll
  for (int i = 0; i < 4; i++)
#pragma unroll
    for (int j = 0; j < 4; j++) acc[i][j] = (f32x4){0.f, 0.f, 0.f, 0.f};

  for (int k0 = 0; k0 < 128; k0 += 64) {
    for (int u = t; u < 1024; u += 256) {
      int row = u >> 3, seg = u & 7;
      *(uint4*)&sA[row][seg * 8] =
          *(const uint4*)(A + (m0 + row) * 128 + k0 + seg * 8);
    }
    for (int u = t; u < 1024; u += 256) {
      int row = u >> 3, seg = u & 7;
      *(uint4*)&sB[row][seg * 8] =
          *(const uint4*)(w2b + (size_t)row * 128 + k0 + seg * 8);
    }
    __syncthreads();
#pragma unroll
    for (int ks = 0; ks < 2; ++ks) {
      const int kk = ks * 32 + quad * 8;
      short8x a[4], bf[4];
#pragma unroll
      for (int i = 0; i < 4; i++)
        a[i] = *reinterpret_cast<const short8x*>(&sA[wm + i * 16 + lr][kk]);
#pragma unroll
      for (int j = 0; j < 4; j++)
        bf[j] = *reinterpret_cast<const short8x*>(&sB[wn + j * 16 + lr][kk]);
#pragma unroll
      for (int i = 0; i < 4; i++)
#pragma unroll
        for (int j = 0; j < 4; j++)
          acc[i][j] = __builtin_amdgcn_mfma_f32_16x16x32_bf16(a[i], bf[j], acc[i][j], 0, 0, 0);
    }
    __syncthreads();
  }
#pragma unroll
  for (int i = 0; i < 4; i++)
#pragma unroll
    for (int r = 0; r < 4; r++) {
      size_t row = m0 + wm + i * 16 + quad * 4 + r;
#pragma unroll
      for (int j = 0; j < 4; j++) {
        int c = wn + j * 16 + lr;
        float v = acc[i][j][r] + b2[c] + us2f(fres[row * 128 + c]);
        X1[row * 128 + c] = f2us(v);
      }
    }
}

// ---------------- K4: fused bidirectional minGRU (MFMA + scans) ----------------
__global__ __launch_bounds__(256) void k_gru(
    const unsigned short* __restrict__ X1, const unsigned short* __restrict__ Wg,
    const unsigned short* __restrict__ Wb, unsigned short* __restrict__ F2) {
  __shared__ unsigned short sA[96][72];
  __shared__ unsigned short sB[256][72];
  __shared__ unsigned short sH[96][136];
  const int t = threadIdx.x;
  const int wave = t >> 6, lane = t & 63, quad = lane >> 4, lr = lane & 15;
  const int blk = blockIdx.x;
  const int b = blk >> 10, p0 = (blk & 1023) << 4;
  f32x4 acc[6][4];
#pragma unroll
  for (int v = 0; v < 6; v++)
#pragma unroll
    for (int j = 0; j < 4; j++) acc[v][j] = (f32x4){0.f, 0.f, 0.f, 0.f};

  // ---- GEMM1: hg1 = X1 . Wg^T (Wg rows interleaved) ----
  for (int k0 = 0; k0 < 128; k0 += 64) {
    for (int u = t; u < 768; u += 256) {
      int r = u >> 3, seg = u & 7;
      int v = r >> 4, ps = r & 15;
      *(uint4*)&sA[r][seg * 8] =
          *(const uint4*)(X1 + ((size_t)((b * 6 + v) * Pc + p0 + ps)) * 128 + k0 + seg * 8);
    }
    for (int u = t; u < 2048; u += 256) {
      int rw = u >> 3, seg = u & 7;
      *(uint4*)&sB[rw][seg * 8] = *(const uint4*)(Wg + (size_t)rw * 128 + k0 + seg * 8);
    }
    __syncthreads();
#pragma unroll
    for (int ks = 0; ks < 2; ++ks) {
      const int kk = ks * 32 + quad * 8;
      short8x a[6], bf[4];
#pragma unroll
      for (int v = 0; v < 6; v++)
        a[v] = *reinterpret_cast<const short8x*>(&sA[v * 16 + lr][kk]);
#pragma unroll
      for (int j = 0; j < 4; j++)
        bf[j] = *reinterpret_cast<const short8x*>(&sB[wave * 64 + j * 16 + lr][kk]);
#pragma unroll
      for (int v = 0; v < 6; v++)
#pragma unroll
        for (int j = 0; j < 4; j++)
          acc[v][j] = __builtin_amdgcn_mfma_f32_16x16x32_bf16(a[v], bf[j], acc[v][j], 0, 0, 0);
    }
    __syncthreads();
  }
  // ---- scan1 (forward over v; flips over H cancel) -> sH [row][d] ----
#pragma unroll
  for (int q = 0; q < 2; q++)
#pragma unroll
    for (int r = 0; r < 4; r++) {
      float h = 0.f;
#pragma unroll
      for (int v = 0; v < 6; v++) {
        float hid = acc[v][2 * q][r], gat = acc[v][2 * q + 1][r];
        float z = sigm(gat);
        float ht = (hid >= 0.f) ? (hid + 0.5f) : sigm(hid);
        h = (1.f - z) * h + z * ht;
        sH[v * 16 + quad * 4 + r][wave * 32 + q * 16 + lr] = f2us(h);
      }
    }
  __syncthreads();

  // ---- GEMM2: hg2 = h1 . Wb^T ----
#pragma unroll
  for (int v = 0; v < 6; v++)
#pragma unroll
    for (int j = 0; j < 4; j++) acc[v][j] = (f32x4){0.f, 0.f, 0.f, 0.f};
  for (int k0 = 0; k0 < 128; k0 += 64) {
    for (int u = t; u < 2048; u += 256) {
      int rw = u >> 3, seg = u & 7;
      *(uint4*)&sB[rw][seg * 8] = *(const uint4*)(Wb + (size_t)rw * 128 + k0 + seg * 8);
    }
    __syncthreads();
#pragma unroll
    for (int ks = 0; ks < 2; ++ks) {
      const int kk = ks * 32 + quad * 8;
      short8x a[6], bf[4];
#pragma unroll
      for (int v = 0; v < 6; v++)
        a[v] = *reinterpret_cast<const short8x*>(&sH[v * 16 + lr][k0 + kk]);
#pragma unroll
      for (int j = 0; j < 4; j++)
        bf[j] = *reinterpret_cast<const short8x*>(&sB[wave * 64 + j * 16 + lr][kk]);
#pragma unroll
      for (int v = 0; v < 6; v++)
#pragma unroll
        for (int j = 0; j < 4; j++)
          acc[v][j] = __builtin_amdgcn_mfma_f32_16x16x32_bf16(a[v], bf[j], acc[v][j], 0, 0, 0);
    }
    __syncthreads();
  }
  // ---- scan2 -> F2 global ----
#pragma unroll
  for (int q = 0; q < 2; q++)
#pragma unroll
    for (int r = 0; r < 4; r++) {
      float h = 0.f;
#pragma unroll
      for (int v = 0; v < 6; v++) {
        float hid = acc[v][2 * q][r], gat = acc[v][2 * q + 1][r];
        float z = sigm(gat);
        float ht = (hid >= 0.f) ? (hid + 0.5f) : sigm(hid);
        h = (1.f - z) * h + z * ht;
        F2[((size_t)((b * 6 + v) * Pc + p0 + quad * 4 + r)) * 128 + wave * 32 + q * 16 + lr] =
            f2us(h);
      }
    }
}

// ---------------- K5+K6 fused: alpha 3x3 conv + softmax over V + pool ----------------
// Wave per (b,pixel): computes alpha for all 6 views (keeping center rows in
// regs), in-wave softmax, weighted pool. Saves the separate 50MB F2 re-read.
__global__ __launch_bounds__(256) void k_apool(
    const unsigned short* __restrict__ F, const float* __restrict__ wa,
    const float* __restrict__ ba, unsigned short* __restrict__ P2) {
  __shared__ float w[Cc * 9];
  for (int i = threadIdx.x; i < Cc * 9; i += 256) w[i] = wa[i];
  __syncthreads();
  const int wave = threadIdx.x >> 6, lane = threadIdx.x & 63;
  const int px = blockIdx.x * 4 + wave;   // over B*P
  const int b = px >> 14, p = px & (Pc - 1);
  const int y = p >> 7, x = p & 127;
  const int c0 = 2 * lane;
  const float* w0 = w + c0 * 9;
  const float* w1 = w + (c0 + 1) * 9;
  float av[Vc];
  ushort2 ctr[Vc];
#pragma unroll
  for (int v = 0; v < Vc; ++v) {
    const unsigned short* Fv = F + ((size_t)((b * Vc + v) * Pc)) * 128;
    float acc = 0.f;
#pragma unroll
    for (int dy = 0; dy < 3; ++dy) {
      int yy = y + dy - 1;
      if (yy < 0 || yy >= Hc) continue;
#pragma unroll
      for (int dx = 0; dx < 3; ++dx) {
        int xx = x + dx - 1;
        if (xx < 0 || xx >= Wc) continue;
        const unsigned short* row = Fv + ((size_t)(yy * Wc + xx)) * 128;
        ushort2 vv = *(const ushort2*)(row + c0);
        if (dy == 1 && dx == 1) ctr[v] = vv;   // center tap always in-bounds
        acc += w0[dy * 3 + dx] * us2f(vv.x) + w1[dy * 3 + dx] * us2f(vv.y);
      }
    }
#pragma unroll
    for (int off = 32; off >= 1; off >>= 1) acc += __shfl_xor(acc, off);
    av[v] = acc + ba[0];
  }
  float mx = -1e30f;
#pragma unroll
  for (int v = 0; v < Vc; ++v) mx = fmaxf(mx, av[v]);
  float s = 0.f;
#pragma unroll
  for (int v = 0; v < Vc; ++v) { av[v] = __expf(av[v] - mx); s += av[v]; }
  const float inv = 1.f / s;
  float a0 = 0.f, a1 = 0.f;
#pragma unroll
  for (int v = 0; v < Vc; ++v) {
    float sw = av[v] * inv;
    a0 += us2f(ctr[v].x) * sw;
    a1 += us2f(ctr[v].y) * sw;
  }
  ushort2 pk;
  pk.x = f2us(a0);
  pk.y = f2us(a1);
  *(ushort2*)(P2 + (size_t)px * 128 + c0) = pk;
}

// ---------------- K7: up 1x1 conv + pixel_shuffle(4) (MFMA) ----------------
__global__ __launch_bounds__(256) void k_up(
    const unsigned short* __restrict__ A, const unsigned short* __restrict__ wub,
    const float* __restrict__ bu, unsigned short* __restrict__ us_) {
  __shared__ unsigned short sA[128][72];
  __shared__ unsigned short sB[128][72];
  const int t = threadIdx.x;
  const int wave = t >> 6, lane = t & 63, quad = lane >> 4, lr = lane & 15;
  const int wm = (wave >> 1) * 64, wn = (wave & 1) * 64;
  const size_t m0 = (size_t)blockIdx.x * 128;
  f32x4 acc[4][4];
#pragma unroll
  for (int i = 0; i < 4; i++)
#pragma unroll
    for (int j = 0; j < 4; j++) acc[i][j] = (f32x4){0.f, 0.f, 0.f, 0.f};

  for (int k0 = 0; k0 < 128; k0 += 64) {
    for (int u = t; u < 1024; u += 256) {
      int row = u >> 3, seg = u & 7;
      *(uint4*)&sA[row][seg * 8] =
          *(const uint4*)(A + (m0 + row) * 128 + k0 + seg * 8);
    }
    for (int u = t; u < 1024; u += 256) {
      int row = u >> 3, seg = u & 7;
      *(uint4*)&sB[row][seg * 8] =
          *(const uint4*)(wub + (size_t)row * 128 + k0 + seg * 8);
    }
    __syncthreads();
#pragma unroll
    for (int ks = 0; ks < 2; ++ks) {
      const int kk = ks * 32 + quad * 8;
      short8x a[4], bf[4];
#pragma unroll
      for (int i = 0; i < 4; i++)
        a[i] = *reinterpret_cast<const short8x*>(&sA[wm + i * 16 + lr][kk]);
#pragma unroll
      for (int j = 0; j < 4; j++)
        bf[j] = *reinterpret_cast<const short8x*>(&sB[wn + j * 16 + lr][kk]);
#pragma unroll
      for (int i = 0; i < 4; i++)
#pragma unroll
        for (int j = 0; j < 4; j++)
          acc[i][j] = __builtin_amdgcn_mfma_f32_16x16x32_bf16(a[i], bf[j], acc[i][j], 0, 0, 0);
    }
    __syncthreads();
  }
#pragma unroll
  for (int i = 0; i < 4; i++)
#pragma unroll
    for (int r = 0; r < 4; r++) {
      size_t row = m0 + wm + i * 16 + quad * 4 + r;   // global pixel (b*P + p)
      int b = (int)(row >> 14), p = (int)(row & (Pc - 1));
      int y = p >> 7, x = p & 127;
#pragma unroll
      for (int j = 0; j < 4; j++) {
        int c = wn + j * 16 + lr;
        float v = acc[i][j][r] + bu[c];
        int co = c >> 4, r1 = (c >> 2) & 3, r2 = c & 3;
        us_[(((size_t)b * 8 + co) * 512 + (y * 4 + r1)) * 512 + (x * 4 + r2)] = f2us(v);
      }
    }
}

// ---------------- K8: 3x3 conv 8->3 on 512x512, fp32 output ----------------
__global__ __launch_bounds__(256) void k_outc(
    const unsigned short* __restrict__ us_, const float* __restrict__ wo,
    const float* __restrict__ bo, float* __restrict__ out) {
  __shared__ float w[3 * 8 * 9];
  for (int i = threadIdx.x; i < 216; i += 256) w[i] = wo[i];
  __syncthreads();
  int i = blockIdx.x;
  const int xh = i & 1; i >>= 1;
  const int Y = i & 511; i >>= 9;
  const int o = i % 3;
  const int b = i / 3;
  const int X = xh * 256 + threadIdx.x;
  float acc = bo[o];
  for (int ci = 0; ci < 8; ++ci) {
    const unsigned short* pl = us_ + ((size_t)b * 8 + ci) * 512 * 512;
    const float* wc = w + o * 72 + ci * 9;
#pragma unroll
    for (int dy = 0; dy < 3; ++dy) {
      int YY = Y + dy - 1;
      if (YY < 0 || YY >= 512) continue;
#pragma unroll
      for (int dx = 0; dx < 3; ++dx) {
        int XX = X + dx - 1;
        if (XX < 0 || XX >= 512) continue;
        acc += wc[dy * 3 + dx] * us2f(pl[(size_t)YY * 512 + XX]);
      }
    }
  }
  out[(((size_t)b * 3 + o) * 512 + Y) * 512 + X] = acc;
}

// ---------------- launcher ----------------
extern "C" void kernel_launch(void* const* d_in, const int* in_sizes, int n_in,
                              void* d_out, int out_size, void* d_ws, size_t ws_size,
                              hipStream_t stream) {
  const float* feats = (const float*)d_in[0];
  const float* prj = (const float*)d_in[1];
  const float* w1 = (const float*)d_in[2];
  const float* b1 = (const float*)d_in[3];
  const float* wd = (const float*)d_in[4];
  const float* bd = (const float*)d_in[5];
  const float* w2 = (const float*)d_in[6];
  const float* b2 = (const float*)d_in[7];
  const float* gw = (const float*)d_in[8];
  const float* gbw = (const float*)d_in[9];
  const float* wa = (const float*)d_in[10];
  const float* ba = (const float*)d_in[11];
  const float* wu = (const float*)d_in[12];
  const float* bu = (const float*)d_in[13];
  const float* wo = (const float*)d_in[14];
  const float* bo = (const float*)d_in[15];
  float* out = (float*)d_out;

  char* ws = (char*)d_ws;
  // big buffers (bf16 [px][128], 50,331,648 B each):
  unsigned short* buf0 = (unsigned short*)(ws + 0);            // m1, then X1
  unsigned short* buf1 = (unsigned short*)(ws + 50331648);     // dwout, then F2
  unsigned short* fres = (unsigned short*)(ws + 100663296);    // bf16 feats
  unsigned short* P2 = (unsigned short*)(ws + 151781376);      // 8,388,608
  unsigned short* ushuf = (unsigned short*)(ws + 160169984);   // 8,388,608
  unsigned short* wbf = (unsigned short*)(ws + 168558592);     // 262,144

  const unsigned short* w1b = wbf;
  const unsigned short* w2b = wbf + 32768;
  const unsigned short* wub = wbf + 49152;
  const unsigned short* wgi = wbf + 65536;
  const unsigned short* wgbi = wbf + 98304;

  dim3 blk(256);
  k_prepw<<<dim3(512), blk, 0, stream>>>(w1, w2, wu, gw, gbw, wbf);
  k_merge1<<<dim3(NPX / 128), blk, 0, stream>>>(feats, prj, w1b, b1, buf0, fres);
  k_dw<<<dim3(NPX / 4), blk, 0, stream>>>(buf0, wd, bd, buf1);
  k_merge2<<<dim3(NPX / 128), blk, 0, stream>>>(buf1, w2b, b2, fres, buf0);
  k_gru<<<dim3(Bc * (Pc / 16)), blk, 0, stream>>>(buf0, wgi, wgbi, buf1);
  k_apool<<<dim3(Bc * Pc / 4), blk, 0, stream>>>(buf1, wa, ba, P2);
  k_up<<<dim3(Bc * Pc / 128), blk, 0, stream>>>(P2, wub, bu, ushuf);
  k_outc<<<dim3(2 * 3 * 512 * 2), blk, 0, stream>>>(ushuf, wo, bo, out);

  (void)in_sizes; (void)n_in; (void)out_size; (void)ws_size;
}

// Round 2
// 669.999 us; speedup vs baseline: 1.1705x; 1.1705x over previous
//
#include <hip/hip_runtime.h>

// GlobalFusion R6: k_merge1 = R4 barrier structure + R5 packed conflict-free
// b128 LDS staging writes, NO cross-step register prefetch (R5's spill bug:
// WRITE_SIZE 98->188MB from scratch). k_apool fusion kept from R5.

#define DEV static __device__ __forceinline__

typedef __attribute__((ext_vector_type(8))) short short8x;
typedef __attribute__((ext_vector_type(4))) float f32x4;

constexpr int Bc = 2, Vc = 6, Cc = 128, Hc = 128, Wc = 128;
constexpr int Nc = Bc * Vc;      // 12
constexpr int Pc = Hc * Wc;      // 16384
constexpr int NPX = Nc * Pc;     // 196608

DEV float us2f(unsigned short u) {
  return __builtin_bit_cast(float, (unsigned int)u << 16);
}
DEV unsigned short f2us(float f) {
  unsigned int i = __builtin_bit_cast(unsigned int, f);
  unsigned int r = i + 0x7FFFu + ((i >> 16) & 1u);   // RNE
  return (unsigned short)(r >> 16);
}
DEV float geluf(float x) { return x * 0.5f * (1.f + erff(x * 0.70710678118654752f)); }
DEV float sigm(float x) { return 1.f / (1.f + __expf(-x)); }

// ---------------- weight prep: fp32 -> bf16 (+ GRU row interleave) ----------------
__global__ __launch_bounds__(256) void k_prepw(
    const float* __restrict__ w1, const float* __restrict__ w2,
    const float* __restrict__ wu, const float* __restrict__ gw,
    const float* __restrict__ gbw, unsigned short* __restrict__ wbf) {
  int idx = blockIdx.x * 256 + threadIdx.x;
  float v;
  if (idx < 32768) {
    v = w1[idx];
  } else if (idx < 49152) {
    v = w2[idx - 32768];
  } else if (idx < 65536) {
    v = wu[idx - 49152];
  } else {
    int i = (idx < 98304) ? (idx - 65536) : (idx - 98304);
    int np = i >> 7, k = i & 127;
    int j = np >> 5, s = np & 31;
    int src = (s < 16) ? (16 * j + s) : (128 + 16 * j + (s - 16));
    const float* w = (idx < 98304) ? gw : gbw;
    v = w[src * 128 + k];
  }
  wbf[idx] = f2us(v);
}

// ---------------- K1: merge 1x1 conv 256->128 + GELU (MFMA) ----------------
// Packed staging: thread owns px=t&127, half ho=t>>7; per k-step loads 4
// octets of 8 fp32 channels (coalesced 256B/wave), packs to bf16, writes
// 4x ds_write_b128 (bank-even). Loads issued before the barrier; staging
// regs dead before MFMA phase (no cross-step liveness).
__global__ __launch_bounds__(256) void k_merge1(
    const float* __restrict__ feats, const float* __restrict__ prj,
    const unsigned short* __restrict__ w1b, const float* __restrict__ b1,
    unsigned short* __restrict__ m1, unsigned short* __restrict__ fres) {
  __shared__ unsigned short sA[128][72];
  __shared__ unsigned short sB[128][72];
  const int t = threadIdx.x;
  const int wave = t >> 6, lane = t & 63, quad = lane >> 4, lr = lane & 15;
  const int wm = (wave >> 1) * 64, wn = (wave & 1) * 64;
  const int mb = blockIdx.x;
  const size_t m0 = (size_t)mb * 128;
  const int n = mb >> 7;
  const int p0 = (mb & 127) << 7;
  const int px = t & 127;     // this thread's A-row
  const int ho = t >> 7;      // 0/1: which half of the 8 channel-octets

  f32x4 acc[4][4];
#pragma unroll
  for (int i = 0; i < 4; i++)
#pragma unroll
    for (int j = 0; j < 4; j++) acc[i][j] = (f32x4){0.f, 0.f, 0.f, 0.f};

#pragma unroll 1
  for (int s = 0; s < 4; ++s) {
    const int k0 = s * 64;
    float ra[4][8];
    uint4 rb[4];
    // issue all global loads for this k-step (in flight across the barrier)
#pragma unroll
    for (int g = 0; g < 4; ++g) {
      const int ch = k0 + 8 * ho + 16 * g;
      const float* src = (ch < 128)
          ? (feats + (size_t)(n * 128 + ch) * Pc)
          : (prj + (size_t)(n * 128 + (ch - 128)) * Pc);
      src += p0 + px;
#pragma unroll
      for (int j = 0; j < 8; ++j) ra[g][j] = src[(size_t)j * Pc];
    }
#pragma unroll
    for (int u = 0; u < 4; ++u) {
      const int id = u * 256 + t;
      const int row = id >> 3, seg = id & 7;
      rb[u] = *(const uint4*)(w1b + (size_t)row * 256 + k0 + seg * 8);
    }
    __syncthreads();          // prev MFMA + fres LDS reads done
    // pack + LDS write (b128, bank-even)
#pragma unroll
    for (int g = 0; g < 4; ++g) {
      unsigned int pk[4];
#pragma unroll
      for (int q2 = 0; q2 < 4; ++q2)
        pk[q2] = (unsigned int)f2us(ra[g][2 * q2]) |
                 ((unsigned int)f2us(ra[g][2 * q2 + 1]) << 16);
      uint4 w4;
      w4.x = pk[0]; w4.y = pk[1]; w4.z = pk[2]; w4.w = pk[3];
      *(uint4*)&sA[px][8 * ho + 16 * g] = w4;
    }
#pragma unroll
    for (int u = 0; u < 4; ++u) {
      const int id = u * 256 + t;
      const int row = id >> 3, seg = id & 7;
      *(uint4*)&sB[row][seg * 8] = rb[u];
    }
    __syncthreads();
#pragma unroll
    for (int ks = 0; ks < 2; ++ks) {
      const int kk = ks * 32 + quad * 8;
      short8x a[4], bf[4];
#pragma unroll
      for (int i = 0; i < 4; i++)
        a[i] = *reinterpret_cast<const short8x*>(&sA[wm + i * 16 + lr][kk]);
#pragma unroll
      for (int j = 0; j < 4; j++)
        bf[j] = *reinterpret_cast<const short8x*>(&sB[wn + j * 16 + lr][kk]);
#pragma unroll
      for (int i = 0; i < 4; i++)
#pragma unroll
        for (int j = 0; j < 4; j++)
          acc[i][j] = __builtin_amdgcn_mfma_f32_16x16x32_bf16(a[i], bf[j], acc[i][j], 0, 0, 0);
    }
    if (k0 < 128) {   // feats slice passthrough -> fres (reads sA)
      for (int u = t; u < 1024; u += 256) {
        int row = u >> 3, seg = u & 7;
        *(uint4*)(fres + (m0 + row) * 128 + k0 + seg * 8) =
            *(const uint4*)&sA[row][seg * 8];
      }
    }
  }
#pragma unroll
  for (int i = 0; i < 4; i++)
#pragma unroll
    for (int r = 0; r < 4; r++) {
      size_t row = m0 + wm + i * 16 + quad * 4 + r;
#pragma unroll
      for (int j = 0; j < 4; j++) {
        int c = wn + j * 16 + lr;
        m1[row * 128 + c] = f2us(geluf(acc[i][j][r] + b1[c]));
      }
    }
}

// ---------------- K2: depthwise 3x3 + GELU ([px][c] layout) ----------------
__global__ __launch_bounds__(256) void k_dw(
    const unsigned short* __restrict__ in, const float* __restrict__ wd,
    const float* __restrict__ bd, unsigned short* __restrict__ out) {
  __shared__ float w[Cc * 9];
  for (int i = threadIdx.x; i < Cc * 9; i += 256) w[i] = wd[i];
  __syncthreads();
  const int wave = threadIdx.x >> 6, lane = threadIdx.x & 63;
  const int pxg = blockIdx.x * 4 + wave;
  const int n = pxg >> 14, p = pxg & (Pc - 1);
  const int y = p >> 7, x = p & 127;
  const int c0 = 2 * lane;
  float a0 = bd[c0], a1 = bd[c0 + 1];
  const float* w0 = w + c0 * 9;
  const float* w1 = w + (c0 + 1) * 9;
#pragma unroll
  for (int dy = 0; dy < 3; ++dy) {
    int yy = y + dy - 1;
    if (yy < 0 || yy >= Hc) continue;
#pragma unroll
    for (int dx = 0; dx < 3; ++dx) {
      int xx = x + dx - 1;
      if (xx < 0 || xx >= Wc) continue;
      const unsigned short* row = in + ((size_t)(n * Pc + yy * Wc + xx)) * 128;
      ushort2 v = *(const ushort2*)(row + c0);
      a0 += w0[dy * 3 + dx] * us2f(v.x);
      a1 += w1[dy * 3 + dx] * us2f(v.y);
    }
  }
  ushort2 pk;
  pk.x = f2us(geluf(a0));
  pk.y = f2us(geluf(a1));
  *(ushort2*)(out + (size_t)pxg * 128 + c0) = pk;
}

// ---------------- K3: merge 1x1 conv 128->128 + bias + residual (MFMA) ----------------
__global__ __launch_bounds__(256) void k_merge2(
    const unsigned short* __restrict__ A, const unsigned short* __restrict__ w2b,
    const float* __restrict__ b2, const unsigned short* __restrict__ fres,
    unsigned short* __restrict__ X1) {
  __shared__ unsigned short sA[128][72];
  __shared__ unsigned short sB[128][72];
  const int t = threadIdx.x;
  const int wave = t >> 6, lane = t & 63, quad = lane >> 4, lr = lane & 15;
  const int wm = (wave >> 1) * 64, wn = (wave & 1) * 64;
  const size_t m0 = (size_t)blockIdx.x * 128;
  f32x4 acc[4][4];
#pragma unroll
  for (int i = 0; i < 4; i++)
#pragma unroll
    for (int j = 0; j < 4; j++) acc[i][j] = (f32x4){0.f, 0.f, 0.f, 0.f};

  for (int k0 = 0; k0 < 128; k0 += 64) {
    for (int u = t; u < 1024; u += 256) {
      int row = u >> 3, seg = u & 7;
      *(uint4*)&sA[row][seg * 8] =
          *(const uint4*)(A + (m0 + row) * 128 + k0 + seg * 8);
    }
    for (int u = t; u < 1024; u += 256) {
      int row = u >> 3, seg = u & 7;
      *(uint4*)&sB[row][seg * 8] =
          *(const uint4*)(w2b + (size_t)row * 128 + k0 + seg * 8);
    }
    __syncthreads();
#pragma unroll
    for (int ks = 0; ks < 2; ++ks) {
      const int kk = ks * 32 + quad * 8;
      short8x a[4], bf[4];
#pragma unroll
      for (int i = 0; i < 4; i++)
        a[i] = *reinterpret_cast<const short8x*>(&sA[wm + i * 16 + lr][kk]);
#pragma unroll
      for (int j = 0; j < 4; j++)
        bf[j] = *reinterpret_cast<const short8x*>(&sB[wn + j * 16 + lr][kk]);
#pragma unroll
      for (int i = 0; i < 4; i++)
#pragma unroll
        for (int j = 0; j < 4; j++)
          acc[i][j] = __builtin_amdgcn_mfma_f32_16x16x32_bf16(a[i], bf[j], acc[i][j], 0, 0, 0);
    }
    __syncthreads();
  }
#pragma unroll
  for (int i = 0; i < 4; i++)
#pragma unroll
    for (int r = 0; r < 4; r++) {
      size_t row = m0 + wm + i * 16 + quad * 4 + r;
#pragma unroll
      for (int j = 0; j < 4; j++) {
        int c = wn + j * 16 + lr;
        float v = acc[i][j][r] + b2[c] + us2f(fres[row * 128 + c]);
        X1[row * 128 + c] = f2us(v);
      }
    }
}

// ---------------- K4: fused bidirectional minGRU (MFMA + scans) ----------------
__global__ __launch_bounds__(256) void k_gru(
    const unsigned short* __restrict__ X1, const unsigned short* __restrict__ Wg,
    const unsigned short* __restrict__ Wb, unsigned short* __restrict__ F2) {
  __shared__ unsigned short sA[96][72];
  __shared__ unsigned short sB[256][72];
  __shared__ unsigned short sH[96][136];
  const int t = threadIdx.x;
  const int wave = t >> 6, lane = t & 63, quad = lane >> 4, lr = lane & 15;
  const int blk = blockIdx.x;
  const int b = blk >> 10, p0 = (blk & 1023) << 4;
  f32x4 acc[6][4];
#pragma unroll
  for (int v = 0; v < 6; v++)
#pragma unroll
    for (int j = 0; j < 4; j++) acc[v][j] = (f32x4){0.f, 0.f, 0.f, 0.f};

  // ---- GEMM1: hg1 = X1 . Wg^T (Wg rows interleaved) ----
  for (int k0 = 0; k0 < 128; k0 += 64) {
    for (int u = t; u < 768; u += 256) {
      int r = u >> 3, seg = u & 7;
      int v = r >> 4, ps = r & 15;
      *(uint4*)&sA[r][seg * 8] =
          *(const uint4*)(X1 + ((size_t)((b * 6 + v) * Pc + p0 + ps)) * 128 + k0 + seg * 8);
    }
    for (int u = t; u < 2048; u += 256) {
      int rw = u >> 3, seg = u & 7;
      *(uint4*)&sB[rw][seg * 8] = *(const uint4*)(Wg + (size_t)rw * 128 + k0 + seg * 8);
    }
    __syncthreads();
#pragma unroll
    for (int ks = 0; ks < 2; ++ks) {
      const int kk = ks * 32 + quad * 8;
      short8x a[6], bf[4];
#pragma unroll
      for (int v = 0; v < 6; v++)
        a[v] = *reinterpret_cast<const short8x*>(&sA[v * 16 + lr][kk]);
#pragma unroll
      for (int j = 0; j < 4; j++)
        bf[j] = *reinterpret_cast<const short8x*>(&sB[wave * 64 + j * 16 + lr][kk]);
#pragma unroll
      for (int v = 0; v < 6; v++)
#pragma unroll
        for (int j = 0; j < 4; j++)
          acc[v][j] = __builtin_amdgcn_mfma_f32_16x16x32_bf16(a[v], bf[j], acc[v][j], 0, 0, 0);
    }
    __syncthreads();
  }
  // ---- scan1 (forward over v; flips over H cancel) -> sH [row][d] ----
#pragma unroll
  for (int q = 0; q < 2; q++)
#pragma unroll
    for (int r = 0; r < 4; r++) {
      float h = 0.f;
#pragma unroll
      for (int v = 0; v < 6; v++) {
        float hid = acc[v][2 * q][r], gat = acc[v][2 * q + 1][r];
        float z = sigm(gat);
        float ht = (hid >= 0.f) ? (hid + 0.5f) : sigm(hid);
        h = (1.f - z) * h + z * ht;
        sH[v * 16 + quad * 4 + r][wave * 32 + q * 16 + lr] = f2us(h);
      }
    }
  __syncthreads();

  // ---- GEMM2: hg2 = h1 . Wb^T ----
#pragma unroll
  for (int v = 0; v < 6; v++)
#pragma unroll
    for (int j = 0; j < 4; j++) acc[v][j] = (f32x4){0.f, 0.f, 0.f, 0.f};
  for (int k0 = 0; k0 < 128; k0 += 64) {
    for (int u = t; u < 2048; u += 256) {
      int rw = u >> 3, seg = u & 7;
      *(uint4*)&sB[rw][seg * 8] = *(const uint4*)(Wb + (size_t)rw * 128 + k0 + seg * 8);
    }
    __syncthreads();
#pragma unroll
    for (int ks = 0; ks < 2; ++ks) {
      const int kk = ks * 32 + quad * 8;
      short8x a[6], bf[4];
#pragma unroll
      for (int v = 0; v < 6; v++)
        a[v] = *reinterpret_cast<const short8x*>(&sH[v * 16 + lr][k0 + kk]);
#pragma unroll
      for (int j = 0; j < 4; j++)
        bf[j] = *reinterpret_cast<const short8x*>(&sB[wave * 64 + j * 16 + lr][kk]);
#pragma unroll
      for (int v = 0; v < 6; v++)
#pragma unroll
        for (int j = 0; j < 4; j++)
          acc[v][j] = __builtin_amdgcn_mfma_f32_16x16x32_bf16(a[v], bf[j], acc[v][j], 0, 0, 0);
    }
    __syncthreads();
  }
  // ---- scan2 -> F2 global ----
#pragma unroll
  for (int q = 0; q < 2; q++)
#pragma unroll
    for (int r = 0; r < 4; r++) {
      float h = 0.f;
#pragma unroll
      for (int v = 0; v < 6; v++) {
        float hid = acc[v][2 * q][r], gat = acc[v][2 * q + 1][r];
        float z = sigm(gat);
        float ht = (hid >= 0.f) ? (hid + 0.5f) : sigm(hid);
        h = (1.f - z) * h + z * ht;
        F2[((size_t)((b * 6 + v) * Pc + p0 + quad * 4 + r)) * 128 + wave * 32 + q * 16 + lr] =
            f2us(h);
      }
    }
}

// ---------------- K5+K6 fused: alpha 3x3 conv + softmax over V + pool ----------------
__global__ __launch_bounds__(256) void k_apool(
    const unsigned short* __restrict__ F, const float* __restrict__ wa,
    const float* __restrict__ ba, unsigned short* __restrict__ P2) {
  __shared__ float w[Cc * 9];
  for (int i = threadIdx.x; i < Cc * 9; i += 256) w[i] = wa[i];
  __syncthreads();
  const int wave = threadIdx.x >> 6, lane = threadIdx.x & 63;
  const int px = blockIdx.x * 4 + wave;   // over B*P
  const int b = px >> 14, p = px & (Pc - 1);
  const int y = p >> 7, x = p & 127;
  const int c0 = 2 * lane;
  const float* w0 = w + c0 * 9;
  const float* w1 = w + (c0 + 1) * 9;
  float av[Vc];
  ushort2 ctr[Vc];
#pragma unroll
  for (int v = 0; v < Vc; ++v) {
    const unsigned short* Fv = F + ((size_t)((b * Vc + v) * Pc)) * 128;
    float acc = 0.f;
#pragma unroll
    for (int dy = 0; dy < 3; ++dy) {
      int yy = y + dy - 1;
      if (yy < 0 || yy >= Hc) continue;
#pragma unroll
      for (int dx = 0; dx < 3; ++dx) {
        int xx = x + dx - 1;
        if (xx < 0 || xx >= Wc) continue;
        const unsigned short* row = Fv + ((size_t)(yy * Wc + xx)) * 128;
        ushort2 vv = *(const ushort2*)(row + c0);
        if (dy == 1 && dx == 1) ctr[v] = vv;   // center tap always in-bounds
        acc += w0[dy * 3 + dx] * us2f(vv.x) + w1[dy * 3 + dx] * us2f(vv.y);
      }
    }
#pragma unroll
    for (int off = 32; off >= 1; off >>= 1) acc += __shfl_xor(acc, off);
    av[v] = acc + ba[0];
  }
  float mx = -1e30f;
#pragma unroll
  for (int v = 0; v < Vc; ++v) mx = fmaxf(mx, av[v]);
  float s = 0.f;
#pragma unroll
  for (int v = 0; v < Vc; ++v) { av[v] = __expf(av[v] - mx); s += av[v]; }
  const float inv = 1.f / s;
  float a0 = 0.f, a1 = 0.f;
#pragma unroll
  for (int v = 0; v < Vc; ++v) {
    float sw = av[v] * inv;
    a0 += us2f(ctr[v].x) * sw;
    a1 += us2f(ctr[v].y) * sw;
  }
  ushort2 pk;
  pk.x = f2us(a0);
  pk.y = f2us(a1);
  *(ushort2*)(P2 + (size_t)px * 128 + c0) = pk;
}

// ---------------- K7: up 1x1 conv + pixel_shuffle(4) (MFMA) ----------------
__global__ __launch_bounds__(256) void k_up(
    const unsigned short* __restrict__ A, const unsigned short* __restrict__ wub,
    const float* __restrict__ bu, unsigned short* __restrict__ us_) {
  __shared__ unsigned short sA[128][72];
  __shared__ unsigned short sB[128][72];
  const int t = threadIdx.x;
  const int wave = t >> 6, lane = t & 63, quad = lane >> 4, lr = lane & 15;
  const int wm = (wave >> 1) * 64, wn = (wave & 1) * 64;
  const size_t m0 = (size_t)blockIdx.x * 128;
  f32x4 acc[4][4];
#pragma unroll
  for (int i = 0; i < 4; i++)
#pragma unroll
    for (int j = 0; j < 4; j++) acc[i][j] = (f32x4){0.f, 0.f, 0.f, 0.f};

  for (int k0 = 0; k0 < 128; k0 += 64) {
    for (int u = t; u < 1024; u += 256) {
      int row = u >> 3, seg = u & 7;
      *(uint4*)&sA[row][seg * 8] =
          *(const uint4*)(A + (m0 + row) * 128 + k0 + seg * 8);
    }
    for (int u = t; u < 1024; u += 256) {
      int row = u >> 3, seg = u & 7;
      *(uint4*)&sB[row][seg * 8] =
          *(const uint4*)(wub + (size_t)row * 128 + k0 + seg * 8);
    }
    __syncthreads();
#pragma unroll
    for (int ks = 0; ks < 2; ++ks) {
      const int kk = ks * 32 + quad * 8;
      short8x a[4], bf[4];
#pragma unroll
      for (int i = 0; i < 4; i++)
        a[i] = *reinterpret_cast<const short8x*>(&sA[wm + i * 16 + lr][kk]);
#pragma unroll
      for (int j = 0; j < 4; j++)
        bf[j] = *reinterpret_cast<const short8x*>(&sB[wn + j * 16 + lr][kk]);
#pragma unroll
      for (int i = 0; i < 4; i++)
#pragma unroll
        for (int j = 0; j < 4; j++)
          acc[i][j] = __builtin_amdgcn_mfma_f32_16x16x32_bf16(a[i], bf[j], acc[i][j], 0, 0, 0);
    }
    __syncthreads();
  }
#pragma unroll
  for (int i = 0; i < 4; i++)
#pragma unroll
    for (int r = 0; r < 4; r++) {
      size_t row = m0 + wm + i * 16 + quad * 4 + r;   // global pixel (b*P + p)
      int b = (int)(row >> 14), p = (int)(row & (Pc - 1));
      int y = p >> 7, x = p & 127;
#pragma unroll
      for (int j = 0; j < 4; j++) {
        int c = wn + j * 16 + lr;
        float v = acc[i][j][r] + bu[c];
        int co = c >> 4, r1 = (c >> 2) & 3, r2 = c & 3;
        us_[(((size_t)b * 8 + co) * 512 + (y * 4 + r1)) * 512 + (x * 4 + r2)] = f2us(v);
      }
    }
}

// ---------------- K8: 3x3 conv 8->3 on 512x512, fp32 output ----------------
__global__ __launch_bounds__(256) void k_outc(
    const unsigned short* __restrict__ us_, const float* __restrict__ wo,
    const float* __restrict__ bo, float* __restrict__ out) {
  __shared__ float w[3 * 8 * 9];
  for (int i = threadIdx.x; i < 216; i += 256) w[i] = wo[i];
  __syncthreads();
  int i = blockIdx.x;
  const int xh = i & 1; i >>= 1;
  const int Y = i & 511; i >>= 9;
  const int o = i % 3;
  const int b = i / 3;
  const int X = xh * 256 + threadIdx.x;
  float acc = bo[o];
  for (int ci = 0; ci < 8; ++ci) {
    const unsigned short* pl = us_ + ((size_t)b * 8 + ci) * 512 * 512;
    const float* wc = w + o * 72 + ci * 9;
#pragma unroll
    for (int dy = 0; dy < 3; ++dy) {
      int YY = Y + dy - 1;
      if (YY < 0 || YY >= 512) continue;
#pragma unroll
      for (int dx = 0; dx < 3; ++dx) {
        int XX = X + dx - 1;
        if (XX < 0 || XX >= 512) continue;
        acc += wc[dy * 3 + dx] * us2f(pl[(size_t)YY * 512 + XX]);
      }
    }
  }
  out[(((size_t)b * 3 + o) * 512 + Y) * 512 + X] = acc;
}

// ---------------- launcher ----------------
extern "C" void kernel_launch(void* const* d_in, const int* in_sizes, int n_in,
                              void* d_out, int out_size, void* d_ws, size_t ws_size,
                              hipStream_t stream) {
  const float* feats = (const float*)d_in[0];
  const float* prj = (const float*)d_in[1];
  const float* w1 = (const float*)d_in[2];
  const float* b1 = (const float*)d_in[3];
  const float* wd = (const float*)d_in[4];
  const float* bd = (const float*)d_in[5];
  const float* w2 = (const float*)d_in[6];
  const float* b2 = (const float*)d_in[7];
  const float* gw = (const float*)d_in[8];
  const float* gbw = (const float*)d_in[9];
  const float* wa = (const float*)d_in[10];
  const float* ba = (const float*)d_in[11];
  const float* wu = (const float*)d_in[12];
  const float* bu = (const float*)d_in[13];
  const float* wo = (const float*)d_in[14];
  const float* bo = (const float*)d_in[15];
  float* out = (float*)d_out;

  char* ws = (char*)d_ws;
  // big buffers (bf16 [px][128], 50,331,648 B each):
  unsigned short* buf0 = (unsigned short*)(ws + 0);            // m1, then X1
  unsigned short* buf1 = (unsigned short*)(ws + 50331648);     // dwout, then F2
  unsigned short* fres = (unsigned short*)(ws + 100663296);    // bf16 feats
  unsigned short* P2 = (unsigned short*)(ws + 151781376);      // 8,388,608
  unsigned short* ushuf = (unsigned short*)(ws + 160169984);   // 8,388,608
  unsigned short* wbf = (unsigned short*)(ws + 168558592);     // 262,144

  const unsigned short* w1b = wbf;
  const unsigned short* w2b = wbf + 32768;
  const unsigned short* wub = wbf + 49152;
  const unsigned short* wgi = wbf + 65536;
  const unsigned short* wgbi = wbf + 98304;

  dim3 blk(256);
  k_prepw<<<dim3(512), blk, 0, stream>>>(w1, w2, wu, gw, gbw, wbf);
  k_merge1<<<dim3(NPX / 128), blk, 0, stream>>>(feats, prj, w1b, b1, buf0, fres);
  k_dw<<<dim3(NPX / 4), blk, 0, stream>>>(buf0, wd, bd, buf1);
  k_merge2<<<dim3(NPX / 128), blk, 0, stream>>>(buf1, w2b, b2, fres, buf0);
  k_gru<<<dim3(Bc * (Pc / 16)), blk, 0, stream>>>(buf0, wgi, wgbi, buf1);
  k_apool<<<dim3(Bc * Pc / 4), blk, 0, stream>>>(buf1, wa, ba, P2);
  k_up<<<dim3(Bc * Pc / 128), blk, 0, stream>>>(P2, wub, bu, ushuf);
  k_outc<<<dim3(2 * 3 * 512 * 2), blk, 0, stream>>>(ushuf, wo, bo, out);

  (void)in_sizes; (void)n_in; (void)out_size; (void)ws_size;
}